// Round 11
// baseline (200.655 us; speedup 1.0000x reference)
//
#include <hip/hip_runtime.h>

typedef __bf16 bf16_t;
typedef __attribute__((ext_vector_type(8))) __bf16 bf16x8;
typedef __attribute__((ext_vector_type(4))) __bf16 bf16x4;
typedef __attribute__((ext_vector_type(4))) float f32x4;
typedef __attribute__((ext_vector_type(16))) float f32x16;
typedef __attribute__((ext_vector_type(2))) unsigned uint2v;

#define MFMA16(a, b, c) __builtin_amdgcn_mfma_f32_16x16x32_bf16((a), (b), (c), 0, 0, 0)
#define MFMA32(a, b, c) __builtin_amdgcn_mfma_f32_32x32x16_bf16((a), (b), (c), 0, 0, 0)
#define LOG2E 1.44269504088896f

// Async global->LDS 16B copy. LDS dest is the WAVE-UNIFORM base; HW places
// lane i's 16B at base + 16*i. gptr is per-lane.
__device__ __forceinline__ void async16(const bf16_t* g, bf16_t* l) {
    __builtin_amdgcn_global_load_lds(
        (const __attribute__((address_space(1))) unsigned int*)g,
        (__attribute__((address_space(3))) unsigned int*)l, 16, 0, 0);
}

__device__ __forceinline__ unsigned pack2(float a, float b) {
    union { bf16_t e[2]; unsigned u; } x;
    x.e[0] = (bf16_t)a; x.e[1] = (bf16_t)b;
    return x.u;
}

// lane[i]<->lane[i+32] half exchange on the VALU pipe (v_permlane32_swap_b32).
__device__ __forceinline__ void pl32swap(unsigned& a, unsigned& b) {
    uint2v r = __builtin_amdgcn_permlane32_swap(a, b, false, false);
    a = r[0]; b = r[1];
}

// Raw workgroup barrier WITHOUT the vmcnt(0) drain of __syncthreads.
__device__ __forceinline__ void pbar() {
    asm volatile("" ::: "memory");
    __builtin_amdgcn_s_barrier();
    asm volatile("" ::: "memory");
}

// ---------------------------------------------------------------------------
// Fused fp32 -> bf16 conversion of x / W_in / W_out into contiguous ws region.
// ---------------------------------------------------------------------------
__global__ __launch_bounds__(256) void conv3(
    const float* __restrict__ s0, const float* __restrict__ s1,
    const float* __restrict__ s2, bf16_t* __restrict__ dst,
    int n0, int n1)
{
    const int i = (blockIdx.x * 256 + threadIdx.x) * 8;
    const float* src;
    int off;
    if (i < n0)           { src = s0; off = 0; }
    else if (i < n0 + n1) { src = s1; off = n0; }
    else                  { src = s2; off = n0 + n1; }
    const float4 a = *reinterpret_cast<const float4*>(src + i - off);
    const float4 b = *reinterpret_cast<const float4*>(src + i - off + 4);
    bf16x8 o;
    o[0] = (bf16_t)a.x; o[1] = (bf16_t)a.y; o[2] = (bf16_t)a.z; o[3] = (bf16_t)a.w;
    o[4] = (bf16_t)b.x; o[5] = (bf16_t)b.y; o[6] = (bf16_t)b.z; o[7] = (bf16_t)b.w;
    *reinterpret_cast<bf16x8*>(dst + i) = o;
}

// ---------------------------------------------------------------------------
// QKV projection GEMM -- 192(f) x 256(m) tile, BK=64, 8 waves, 4-phase
// quadrant schedule, 256 blocks = 1/CU (R8-verified).
// V third (f>=2048) is written PRE-FRAGMENTED for flash's PV consumption:
//   vF[((bh*32 + tile)*8 + chunk)*64 + d][8]  (elems; 16B unit = one MFMA
//   B-fragment slice), where tile = s>>6, chunk = (s>>3)&7 selects the
//   8-wide k-slice (kn*2+half in flash), d = head dim, k0 = s&7.
// Flash then loads each vfr[kn][dt] as TWO CONTIGUOUS 512B segments from
// global -- the coalesced version of R5's V-direct idea (R5's 11us loss was
// the d*2048-stride gather; layout ownership via the fused epilogue fixes it).
// ---------------------------------------------------------------------------
__global__ __launch_bounds__(512, 2) void gemm_qkv(
    const bf16_t* __restrict__ W, const bf16_t* __restrict__ X,
    const float* __restrict__ bias, bf16_t* __restrict__ qkv,
    bf16_t* __restrict__ vtp)
{
    constexpr int K = 1024;
    constexpr int NSTEP = K / 64;        // 16
    constexpr int AELEM = 192 * 64;      // 12288 elems = 24 KB
    constexpr int BELEM = 256 * 64;      // 16384 elems = 32 KB

    __shared__ bf16_t lds[2][AELEM + BELEM];   // 112 KB total

    const int tid  = threadIdx.x;        // 0..511
    const int lane = tid & 63;
    const int wv   = tid >> 6;           // 0..7
    const int wm   = wv >> 2;            // f-half of 192 (96 rows each)
    const int wn   = wv & 3;             // m-quarter of 256 (64 rows each)
    const int l15  = lane & 15;
    const int qd   = lane >> 4;

    const int id = blockIdx.x;           // 0..255
    const int x8 = id & 7, k = id >> 3;  // k 0..31
    const int mb = ((k & 1) * 8 + x8) * 256;
    const int fb = (k >> 1) * 192;

    f32x4 acc[6][4] = {};                // [i: f frag 0..5][j: m frag 0..3]

    auto stage = [&](int set, int k0) {
        bf16_t* Ab = lds[set];
        bf16_t* Bb = lds[set] + AELEM;
#pragma unroll
        for (int t = 0; t < 3; t++) {    // A: 192 rows = 1536 chunks
            const int p = t * 512 + tid;
            const int r = p >> 3;
            const int c = (p & 7) ^ (r & 7);
            async16(W + (size_t)(fb + r) * K + k0 + c * 8,
                    Ab + (t * 512 + wv * 64) * 8);
        }
#pragma unroll
        for (int t = 0; t < 4; t++) {    // B: 256 rows = 2048 chunks
            const int p = t * 512 + tid;
            const int r = p >> 3;
            const int c = (p & 7) ^ (r & 7);
            async16(X + (size_t)(mb + r) * K + k0 + c * 8,
                    Bb + (t * 512 + wv * 64) * 8);
        }
    };

    stage(0, 0);                         // prologue: step 0 -> buf 0
    for (int s = 0; s < NSTEP; s++) {
        const int set = s & 1;
        __syncthreads();                 // buf[set] staging drained; fence
        if (s + 1 < NSTEP) stage(set ^ 1, (s + 1) * 64);

        const bf16_t* Ab = lds[set];
        const bf16_t* Bb = lds[set] + AELEM;

        bf16x8 a0[3][2], a1[3][2], b0[2][2], b1[2][2];

        // ---- phase 1: Q(0,0) -- load a0 (i=0..2), b0 (j=0..1) ----
#pragma unroll
        for (int i = 0; i < 3; i++) {
            const int r = wm * 96 + i * 16 + l15;
            a0[i][0] = *reinterpret_cast<const bf16x8*>(
                Ab + r * 64 + ((qd ^ (r & 7)) * 8));
            a0[i][1] = *reinterpret_cast<const bf16x8*>(
                Ab + r * 64 + (((4 + qd) ^ (r & 7)) * 8));
        }
#pragma unroll
        for (int j = 0; j < 2; j++) {
            const int r = wn * 64 + j * 16 + l15;
            b0[j][0] = *reinterpret_cast<const bf16x8*>(
                Bb + r * 64 + ((qd ^ (r & 7)) * 8));
            b0[j][1] = *reinterpret_cast<const bf16x8*>(
                Bb + r * 64 + (((4 + qd) ^ (r & 7)) * 8));
        }
        __builtin_amdgcn_s_setprio(1);
#pragma unroll
        for (int i = 0; i < 3; i++)
#pragma unroll
            for (int j = 0; j < 2; j++) {
                acc[i][j] = MFMA16(a0[i][0], b0[j][0], acc[i][j]);
                acc[i][j] = MFMA16(a0[i][1], b0[j][1], acc[i][j]);
            }
        __builtin_amdgcn_s_setprio(0);
        pbar();

        // ---- phase 2: Q(1,0) -- load a1 (i=3..5), reuse b0 ----
#pragma unroll
        for (int i = 0; i < 3; i++) {
            const int r = wm * 96 + (i + 3) * 16 + l15;
            a1[i][0] = *reinterpret_cast<const bf16x8*>(
                Ab + r * 64 + ((qd ^ (r & 7)) * 8));
            a1[i][1] = *reinterpret_cast<const bf16x8*>(
                Ab + r * 64 + (((4 + qd) ^ (r & 7)) * 8));
        }
        __builtin_amdgcn_s_setprio(1);
#pragma unroll
        for (int i = 0; i < 3; i++)
#pragma unroll
            for (int j = 0; j < 2; j++) {
                acc[i + 3][j] = MFMA16(a1[i][0], b0[j][0], acc[i + 3][j]);
                acc[i + 3][j] = MFMA16(a1[i][1], b0[j][1], acc[i + 3][j]);
            }
        __builtin_amdgcn_s_setprio(0);
        pbar();

        // ---- phase 3: Q(1,1) -- load b1 (j=2..3), reuse a1 ----
#pragma unroll
        for (int j = 0; j < 2; j++) {
            const int r = wn * 64 + (j + 2) * 16 + l15;
            b1[j][0] = *reinterpret_cast<const bf16x8*>(
                Bb + r * 64 + ((qd ^ (r & 7)) * 8));
            b1[j][1] = *reinterpret_cast<const bf16x8*>(
                Bb + r * 64 + (((4 + qd) ^ (r & 7)) * 8));
        }
        __builtin_amdgcn_s_setprio(1);
#pragma unroll
        for (int i = 0; i < 3; i++)
#pragma unroll
            for (int j = 0; j < 2; j++) {
                acc[i + 3][j + 2] = MFMA16(a1[i][0], b1[j][0], acc[i + 3][j + 2]);
                acc[i + 3][j + 2] = MFMA16(a1[i][1], b1[j][1], acc[i + 3][j + 2]);
            }
        __builtin_amdgcn_s_setprio(0);
        pbar();

        // ---- phase 4: Q(0,1) -- reuse a0, b1 (no reads) ----
        __builtin_amdgcn_s_setprio(1);
#pragma unroll
        for (int i = 0; i < 3; i++)
#pragma unroll
            for (int j = 0; j < 2; j++) {
                acc[i][j + 2] = MFMA16(a0[i][0], b1[j][0], acc[i][j + 2]);
                acc[i][j + 2] = MFMA16(a0[i][1], b1[j][1], acc[i][j + 2]);
            }
        __builtin_amdgcn_s_setprio(0);
    }

    // ---- epilogue: bias + per-i scale; V third pre-fragmented into vF ----
#pragma unroll
    for (int i = 0; i < 6; i++) {
        const int f0i = fb + wm * 96 + i * 16;       // 16-aligned group base
        const int f0  = f0i + qd * 4;
        const float scale = (f0i < 1024) ? 0.125f * LOG2E : 1.0f;
        const bool vblk = (f0i >= 2048);
        float bs[4];
#pragma unroll
        for (int r = 0; r < 4; r++) bs[r] = bias[f0 + r];
#pragma unroll
        for (int j = 0; j < 4; j++) {
            const int m = mb + wn * 64 + j * 16 + l15;
            if (vblk) {
                const int sIdx = m >> 1;          // B = 2 row interleave
                const int b2   = (m & 1) << 4;    // b*16
                const int t    = sIdx >> 6;       // kv tile
                const int ch   = (sIdx >> 3) & 7; // 8-wide k-slice in tile
                const int k0   = sIdx & 7;        // pos within slice
#pragma unroll
                for (int r = 0; r < 4; r++) {
                    const int fv = f0 + r - 2048;
                    const int bh = b2 + (fv >> 6);
                    const int d  = fv & 63;
                    vtp[(size_t)(bh * 32 + t) * 4096 + ch * 512 + d * 8 + k0] =
                        (bf16_t)(acc[i][j][r] + bs[r]);
                }
            } else {
                bf16x4 o;
#pragma unroll
                for (int r = 0; r < 4; r++)
                    o[r] = (bf16_t)((acc[i][j][r] + bs[r]) * scale);
                *reinterpret_cast<bf16x4*>(qkv + (size_t)m * 3072 + f0) = o;
            }
        }
    }
}

// ---------------------------------------------------------------------------
// Output projection GEMM -- 64(f) x 256(m) tile, BK=64, 8 waves, 2-sub-phase
// schedule, 256 blocks = 1/CU (R10: ~neutral vs 2-phase; kept).
// ---------------------------------------------------------------------------
__global__ __launch_bounds__(512, 2) void gemm_out(
    const bf16_t* __restrict__ W, const bf16_t* __restrict__ X,
    const float* __restrict__ bias, float* __restrict__ out)
{
    constexpr int K = 1024;
    constexpr int NSTEP = K / 64;        // 16
    constexpr int AELEM = 64 * 64;       // 8 KB
    constexpr int BELEM = 256 * 64;      // 32 KB

    __shared__ bf16_t lds[2][AELEM + BELEM];   // 80 KB total

    const int tid  = threadIdx.x;        // 0..511
    const int lane = tid & 63;
    const int wv   = tid >> 6;           // 0..7
    const int wm   = wv >> 2;            // f-half (32 rows each)
    const int wn   = wv & 3;             // m-quarter (64 rows each)
    const int l15  = lane & 15;
    const int qd   = lane >> 4;

    const int id = blockIdx.x;           // 0..255
    const int x8 = id & 7, k = id >> 3;  // k 0..31
    const int mb = ((k & 1) * 8 + x8) * 256;
    const int fb = (k >> 1) * 64;

    f32x4 acc[2][4] = {};                // [i: f frag 0..1][j: m frag 0..3]

    auto stage = [&](int set, int k0) {
        bf16_t* Ab = lds[set];
        bf16_t* Bb = lds[set] + AELEM;
        {                                // A: 64 rows = 512 chunks (1/thread)
            const int p = tid;
            const int r = p >> 3;
            const int c = (p & 7) ^ (r & 7);
            async16(W + (size_t)(fb + r) * K + k0 + c * 8,
                    Ab + (wv * 64) * 8);
        }
#pragma unroll
        for (int t = 0; t < 4; t++) {    // B: 256 rows = 2048 chunks
            const int p = t * 512 + tid;
            const int r = p >> 3;
            const int c = (p & 7) ^ (r & 7);
            async16(X + (size_t)(mb + r) * K + k0 + c * 8,
                    Bb + (t * 512 + wv * 64) * 8);
        }
    };

    stage(0, 0);
    for (int s = 0; s < NSTEP; s++) {
        const int set = s & 1;
        __syncthreads();                 // buf[set] staging drained; fence
        if (s + 1 < NSTEP) stage(set ^ 1, (s + 1) * 64);

        const bf16_t* Ab = lds[set];
        const bf16_t* Bb = lds[set] + AELEM;

        bf16x8 a[2][2], b0[2][2], b1[2][2];

        // ---- sub-phase 1: all a + b-half 0 (j=0..1) ----
#pragma unroll
        for (int i = 0; i < 2; i++) {
            const int r = wm * 32 + i * 16 + l15;
            a[i][0] = *reinterpret_cast<const bf16x8*>(
                Ab + r * 64 + ((qd ^ (r & 7)) * 8));
            a[i][1] = *reinterpret_cast<const bf16x8*>(
                Ab + r * 64 + (((4 + qd) ^ (r & 7)) * 8));
        }
#pragma unroll
        for (int j = 0; j < 2; j++) {
            const int r = wn * 64 + j * 16 + l15;
            b0[j][0] = *reinterpret_cast<const bf16x8*>(
                Bb + r * 64 + ((qd ^ (r & 7)) * 8));
            b0[j][1] = *reinterpret_cast<const bf16x8*>(
                Bb + r * 64 + (((4 + qd) ^ (r & 7)) * 8));
        }
        __builtin_amdgcn_s_setprio(1);
#pragma unroll
        for (int i = 0; i < 2; i++)
#pragma unroll
            for (int j = 0; j < 2; j++) {
                acc[i][j] = MFMA16(a[i][0], b0[j][0], acc[i][j]);
                acc[i][j] = MFMA16(a[i][1], b0[j][1], acc[i][j]);
            }
        __builtin_amdgcn_s_setprio(0);
        pbar();

        // ---- sub-phase 2: b-half 1 (j=2..3), reuse a ----
#pragma unroll
        for (int j = 0; j < 2; j++) {
            const int r = wn * 64 + (j + 2) * 16 + l15;
            b1[j][0] = *reinterpret_cast<const bf16x8*>(
                Bb + r * 64 + ((qd ^ (r & 7)) * 8));
            b1[j][1] = *reinterpret_cast<const bf16x8*>(
                Bb + r * 64 + (((4 + qd) ^ (r & 7)) * 8));
        }
        __builtin_amdgcn_s_setprio(1);
#pragma unroll
        for (int i = 0; i < 2; i++)
#pragma unroll
            for (int j = 0; j < 2; j++) {
                acc[i][j + 2] = MFMA16(a[i][0], b1[j][0], acc[i][j + 2]);
                acc[i][j + 2] = MFMA16(a[i][1], b1[j][1], acc[i][j + 2]);
            }
        __builtin_amdgcn_s_setprio(0);
    }

    // ---- epilogue: bias, f32 stores ----
#pragma unroll
    for (int i = 0; i < 2; i++) {
        const int f0 = fb + wm * 32 + i * 16 + qd * 4;
        float bs[4];
#pragma unroll
        for (int r = 0; r < 4; r++) bs[r] = bias[f0 + r];
#pragma unroll
        for (int j = 0; j < 4; j++) {
            const int m = mb + wn * 64 + j * 16 + l15;
            float4 o;
            o.x = acc[i][j][0] + bs[0];
            o.y = acc[i][j][1] + bs[1];
            o.z = acc[i][j][2] + bs[2];
            o.w = acc[i][j][3] + bs[3];
            *reinterpret_cast<float4*>(out + (size_t)m * 1024 + f0) = o;
        }
    }
}

// ---------------------------------------------------------------------------
// Flash attention, IN-BLOCK KV-split x2, V DIRECT FROM PRE-FRAGMENTED GLOBAL.
// Block = 4 waves / 128 q: wave = {pr = wv>>1 (KV half), qw = wv&1 (64-q
// sub-block)}. Grid 32 bh x 16 = 512 blocks (2/CU, grid-capped).
// K keeps its double-buffered LDS + async16 prefetch pipeline (1 barrier/
// iter). V has NO LDS: vfr[kn][dt] loads from vF as two contiguous 512B
// segments per instruction (layout written by gemm_qkv's epilogue), issued
// at iter top so the QK+softmax phase (~2k cyc) hides their L2 latency.
// Removes per-wave-iter: 4 async16 issues + 8 ds_read_b128 + half the
// barrier vmcnt-drain mass; LDS 66 -> ~33 KB.
// __launch_bounds__(256,1): lifts the allocator's 128-VGPR target (R5/R9
// showed it spills rather than exceed 128); occupancy stays grid-capped.
// PV values and kn->dt->qt order identical to R2 -> bit-identical output.
// ---------------------------------------------------------------------------
__global__ __launch_bounds__(256, 1) void flash_attn(
    const bf16_t* __restrict__ qkv, const bf16_t* __restrict__ vF,
    bf16_t* __restrict__ attn, int S, int B)
{
    const int E3 = 3072, E = 1024;
    const int bh = blockIdx.x, b = bh >> 4, h = bh & 15;
    const int tid = threadIdx.x, lane = tid & 63, wv = tid >> 6;  // 0..3
    const int qw = wv & 1;               // q sub-block (64 q each)
    const int pr = wv >> 1;              // KV half
    const int l31 = lane & 31, half = lane >> 5;

    __shared__ bf16_t Kt[2][2][64 * 64];  // [pair][set]; chunk c at c^(r&7)
    __shared__ float  lsh[2][64];

    const int q0 = blockIdx.y * 128 + qw * 64;

    bf16x8 qf[2][4];                     // Q[q][k = ks*16 + half*8 + j]
#pragma unroll
    for (int qt = 0; qt < 2; qt++) {
        const bf16_t* qp = qkv + (size_t)((q0 + qt * 32 + l31) * B + b) * E3 + h * 64;
#pragma unroll
        for (int ks = 0; ks < 4; ks++)
            qf[qt][ks] = *reinterpret_cast<const bf16x8*>(qp + ks * 16 + half * 8);
    }

    f32x16 oacc[2][2] = {};              // [qt][d-tile]; row=d col=q
    float lrun[2] = {0.0f, 0.0f};

    auto stageK = [&](int set_, int kv) {
#pragma unroll
        for (int t = 0; t < 4; t++) {
            const int p = (qw * 4 + t) * 64 + lane;     // phys chunk 0..511
            const int r = p >> 3, cl = (p & 7) ^ (r & 7);
            async16(qkv + (size_t)((kv + r) * B + b) * E3 + E + h * 64 + cl * 8,
                    &Kt[pr][set_][(qw * 4 + t) * 512]);
        }
    };

    const int kvbase = pr * (S / 2);
    const int NIT = S / 128;             // 16 iters of 64 per pair
    // vF fragment base for this head: vF[(bh*32 + tile)*4096 + ...]
    const bf16_t* Vhead = vF + (size_t)(bh * 32) * 4096;

    stageK(0, kvbase);
    int set = 0;
    for (int it = 0; it < NIT; it++) {
        __syncthreads();                 // K[set] ready; K[set^1] free
        if (it + 1 < NIT) stageK(set ^ 1, kvbase + (it + 1) * 64);

        // V fragments for this tile: issued early, consumed in PV after the
        // QK+softmax phase (hides L2 latency). Two 512B segments per load.
        const bf16_t* Vg = Vhead + (size_t)(pr * 16 + it) * 4096;
        bf16x8 vfr[4][2];
#pragma unroll
        for (int kn = 0; kn < 4; kn++)
#pragma unroll
            for (int dt = 0; dt < 2; dt++)
                vfr[kn][dt] = *reinterpret_cast<const bf16x8*>(
                    Vg + (kn * 2 + half) * 512 + (dt * 32 + l31) * 8);

        const bf16_t* K_ = Kt[pr][set];

        union PF { unsigned u[4]; bf16x8 v; };
        PF pf[2][4];
#pragma unroll
        for (int nt = 0; nt < 2; nt++) {
            const int r = nt * 32 + l31;
            const int r7 = r & 7;
            bf16x8 kf[4];
#pragma unroll
            for (int ks = 0; ks < 4; ks++)
                kf[ks] = *reinterpret_cast<const bf16x8*>(
                    K_ + r * 64 + (((ks * 2 + half) ^ r7) * 8));
#pragma unroll
            for (int qt = 0; qt < 2; qt++) {
                f32x16 st = {};
                __builtin_amdgcn_s_setprio(1);
#pragma unroll
                for (int ks = 0; ks < 4; ks++)
                    st = MFMA32(kf[ks], qf[qt][ks], st);
                __builtin_amdgcn_s_setprio(0);
                float ls = 0.0f;
                unsigned q8[8];
#pragma unroll
                for (int g = 0; g < 4; g++) {
                    const float p0 = __builtin_amdgcn_exp2f(st[4 * g]);
                    const float p1 = __builtin_amdgcn_exp2f(st[4 * g + 1]);
                    const float p2 = __builtin_amdgcn_exp2f(st[4 * g + 2]);
                    const float p3 = __builtin_amdgcn_exp2f(st[4 * g + 3]);
                    ls += (p0 + p1) + (p2 + p3);
                    q8[2 * g]     = pack2(p0, p1);
                    q8[2 * g + 1] = pack2(p2, p3);
                }
                lrun[qt] += ls;
                pl32swap(q8[0], q8[2]); pl32swap(q8[1], q8[3]);
                pl32swap(q8[4], q8[6]); pl32swap(q8[5], q8[7]);
                pf[qt][nt * 2 + 0].u[0] = q8[0]; pf[qt][nt * 2 + 0].u[1] = q8[1];
                pf[qt][nt * 2 + 0].u[2] = q8[2]; pf[qt][nt * 2 + 0].u[3] = q8[3];
                pf[qt][nt * 2 + 1].u[0] = q8[4]; pf[qt][nt * 2 + 1].u[1] = q8[5];
                pf[qt][nt * 2 + 1].u[2] = q8[6]; pf[qt][nt * 2 + 1].u[3] = q8[7];
            }
        }
        __builtin_amdgcn_s_setprio(1);
#pragma unroll
        for (int kn = 0; kn < 4; kn++)
#pragma unroll
            for (int dt = 0; dt < 2; dt++) {
                oacc[0][dt] = MFMA32(vfr[kn][dt], pf[0][kn].v, oacc[0][dt]);
                oacc[1][dt] = MFMA32(vfr[kn][dt], pf[1][kn].v, oacc[1][dt]);
            }
        __builtin_amdgcn_s_setprio(0);
        set ^= 1;
    }

    // --- Epilogue: merge the two KV halves through LDS, normalize, store ---
    __syncthreads();                     // all K reads done; LDS reusable
    float lr[2];
#pragma unroll
    for (int qt = 0; qt < 2; qt++) lr[qt] = lrun[qt] + __shfl_xor(lrun[qt], 32);

    // fp32 scratch overlays Kt (32 KB = 2 regions x 64q x 64d), d-major
    float* fo = reinterpret_cast<float*>(&Kt[0][0][0]) + qw * 4096;

    if (pr == 1) {
#pragma unroll
        for (int qt = 0; qt < 2; qt++) {
            const int ql = qt * 32 + l31;
            lsh[qw][ql] = lr[qt];        // both halves write same value
#pragma unroll
            for (int dt = 0; dt < 2; dt++)
#pragma unroll
                for (int g = 0; g < 4; g++)
#pragma unroll
                    for (int r = 0; r < 4; r++) {
                        const int d = dt * 32 + g * 8 + half * 4 + r;
                        fo[d * 64 + ql] = oacc[qt][dt][4 * g + r];
                    }
        }
    }
    __syncthreads();
    if (pr == 0) {
#pragma unroll
        for (int qt = 0; qt < 2; qt++) {
            const int ql = qt * 32 + l31;
            const float inv = 1.0f / (lr[qt] + lsh[qw][ql]);
            const int qrow = q0 + qt * 32 + l31;
#pragma unroll
            for (int dt = 0; dt < 2; dt++)
#pragma unroll
                for (int g = 0; g < 4; g++) {
                    bf16x4 o;
#pragma unroll
                    for (int r = 0; r < 4; r++) {
                        const int d = dt * 32 + g * 8 + half * 4 + r;
                        o[r] = (bf16_t)((oacc[qt][dt][4 * g + r] + fo[d * 64 + ql]) * inv);
                    }
                    *reinterpret_cast<bf16x4*>(attn + (size_t)(qrow * B + b) * E +
                                               h * 64 + dt * 32 + g * 8 + half * 4) = o;
                }
        }
    }
}

extern "C" void kernel_launch(void* const* d_in, const int* in_sizes, int n_in,
                              void* d_out, int out_size, void* d_ws, size_t ws_size,
                              hipStream_t stream) {
    const float* x  = (const float*)d_in[0];
    const float* wi = (const float*)d_in[1];
    const float* bi = (const float*)d_in[2];
    const float* wo = (const float*)d_in[3];
    const float* bo = (const float*)d_in[4];
    float* out = (float*)d_out;

    const int S = 2048, B = 2, E = 1024;
    const int M = S * B;

    // Workspace layout:
    //   xb [M,1024] bf16  -- X in bf16; dead after QKV GEMM
    //   wib[3072,1024]    -- W_in bf16
    //   wob[1024,1024]    -- W_out bf16
    //   qkv[M,3072]       -- Q,K written by GEMM; V third left unwritten
    //   vF [32*32*4096]   -- V pre-fragmented (8.4 MB), by the GEMM epilogue
    //   attn = xb overlay -- flash output (xb dead by then)
    bf16_t* xb   = (bf16_t*)d_ws;
    bf16_t* wib  = xb  + (size_t)M * E;
    bf16_t* wob  = wib + (size_t)3 * E * E;
    bf16_t* qkv  = wob + (size_t)E * E;
    bf16_t* vF   = qkv + (size_t)M * 3 * E;
    bf16_t* attn = xb;

    // 0) fused fp32 -> bf16
    const int n0 = M * E, n1 = 3 * E * E, n2 = E * E;
    conv3<<<(n0 + n1 + n2) / 8 / 256, 256, 0, stream>>>(x, wi, wo, xb, n0, n1);

    // 1) QKV projection: 192x256 4-phase template, 256 blocks = 1/CU;
    //    V third written pre-fragmented into vF; qscale folded into q.
    gemm_qkv<<<256, 512, 0, stream>>>(wib, xb, bi, qkv, vF);

    // 2) Flash attention (K in LDS; V direct from fragmented global)
    flash_attn<<<dim3(B * 16, S / 128), 256, 0, stream>>>(qkv, vF, attn, S, B);

    // 3) Output projection: 64x256 phased template, 256 blocks = 1/CU
    gemm_out<<<256, 512, 0, stream>>>(wob, attn, bo, out);
}

// Round 12
// 177.578 us; speedup vs baseline: 1.1300x; 1.1300x over previous
//
#include <hip/hip_runtime.h>

typedef __bf16 bf16_t;
typedef __attribute__((ext_vector_type(8))) __bf16 bf16x8;
typedef __attribute__((ext_vector_type(4))) __bf16 bf16x4;
typedef __attribute__((ext_vector_type(4))) float f32x4;
typedef __attribute__((ext_vector_type(16))) float f32x16;
typedef __attribute__((ext_vector_type(2))) unsigned uint2v;

#define MFMA16(a, b, c) __builtin_amdgcn_mfma_f32_16x16x32_bf16((a), (b), (c), 0, 0, 0)
#define MFMA32(a, b, c) __builtin_amdgcn_mfma_f32_32x32x16_bf16((a), (b), (c), 0, 0, 0)
#define LOG2E 1.44269504088896f

// Async global->LDS 16B copy. LDS dest is the WAVE-UNIFORM base; HW places
// lane i's 16B at base + 16*i. gptr is per-lane.
__device__ __forceinline__ void async16(const bf16_t* g, bf16_t* l) {
    __builtin_amdgcn_global_load_lds(
        (const __attribute__((address_space(1))) unsigned int*)g,
        (__attribute__((address_space(3))) unsigned int*)l, 16, 0, 0);
}

__device__ __forceinline__ unsigned pack2(float a, float b) {
    union { bf16_t e[2]; unsigned u; } x;
    x.e[0] = (bf16_t)a; x.e[1] = (bf16_t)b;
    return x.u;
}

// lane[i]<->lane[i+32] half exchange on the VALU pipe (v_permlane32_swap_b32).
__device__ __forceinline__ void pl32swap(unsigned& a, unsigned& b) {
    uint2v r = __builtin_amdgcn_permlane32_swap(a, b, false, false);
    a = r[0]; b = r[1];
}

// Raw workgroup barrier WITHOUT the vmcnt(0) drain of __syncthreads.
__device__ __forceinline__ void pbar() {
    asm volatile("" ::: "memory");
    __builtin_amdgcn_s_barrier();
    asm volatile("" ::: "memory");
}

// ---------------------------------------------------------------------------
// Fused fp32 -> bf16 conversion of x / W_in / W_out into contiguous ws region.
// ---------------------------------------------------------------------------
__global__ __launch_bounds__(256) void conv3(
    const float* __restrict__ s0, const float* __restrict__ s1,
    const float* __restrict__ s2, bf16_t* __restrict__ dst,
    int n0, int n1)
{
    const int i = (blockIdx.x * 256 + threadIdx.x) * 8;
    const float* src;
    int off;
    if (i < n0)           { src = s0; off = 0; }
    else if (i < n0 + n1) { src = s1; off = n0; }
    else                  { src = s2; off = n0 + n1; }
    const float4 a = *reinterpret_cast<const float4*>(src + i - off);
    const float4 b = *reinterpret_cast<const float4*>(src + i - off + 4);
    bf16x8 o;
    o[0] = (bf16_t)a.x; o[1] = (bf16_t)a.y; o[2] = (bf16_t)a.z; o[3] = (bf16_t)a.w;
    o[4] = (bf16_t)b.x; o[5] = (bf16_t)b.y; o[6] = (bf16_t)b.z; o[7] = (bf16_t)b.w;
    *reinterpret_cast<bf16x8*>(dst + i) = o;
}

// ---------------------------------------------------------------------------
// QKV projection GEMM -- 192(f) x 256(m) tile, BK=64, 8 waves, 4-phase
// quadrant schedule, 256 blocks = 1/CU (R8-verified: the phased schedule is
// +33% per-CU vs the 2-phase 128^2 baseline at full subscription).
// V third (f>=2048) written TRANSPOSED into vT[bh][d][s] (fused vtrans,
// R6-verified). NOTE (R11): do NOT replace vT-LDS-staging in flash with
// direct global fragment loads -- vmcnt retires in issue order, so PV's
// wait on late-issued V loads drains the K prefetch too (serializes the
// pipeline; 54 -> 78 us). V-direct family closed after 3 attempts.
// ---------------------------------------------------------------------------
__global__ __launch_bounds__(512, 2) void gemm_qkv(
    const bf16_t* __restrict__ W, const bf16_t* __restrict__ X,
    const float* __restrict__ bias, bf16_t* __restrict__ qkv,
    bf16_t* __restrict__ vtp)
{
    constexpr int K = 1024;
    constexpr int NSTEP = K / 64;        // 16
    constexpr int AELEM = 192 * 64;      // 12288 elems = 24 KB
    constexpr int BELEM = 256 * 64;      // 16384 elems = 32 KB

    __shared__ bf16_t lds[2][AELEM + BELEM];   // 112 KB total

    const int tid  = threadIdx.x;        // 0..511
    const int lane = tid & 63;
    const int wv   = tid >> 6;           // 0..7
    const int wm   = wv >> 2;            // f-half of 192 (96 rows each)
    const int wn   = wv & 3;             // m-quarter of 256 (64 rows each)
    const int l15  = lane & 15;
    const int qd   = lane >> 4;

    const int id = blockIdx.x;           // 0..255
    const int x8 = id & 7, k = id >> 3;  // k 0..31
    const int mb = ((k & 1) * 8 + x8) * 256;
    const int fb = (k >> 1) * 192;

    f32x4 acc[6][4] = {};                // [i: f frag 0..5][j: m frag 0..3]

    auto stage = [&](int set, int k0) {
        bf16_t* Ab = lds[set];
        bf16_t* Bb = lds[set] + AELEM;
#pragma unroll
        for (int t = 0; t < 3; t++) {    // A: 192 rows = 1536 chunks
            const int p = t * 512 + tid;
            const int r = p >> 3;
            const int c = (p & 7) ^ (r & 7);
            async16(W + (size_t)(fb + r) * K + k0 + c * 8,
                    Ab + (t * 512 + wv * 64) * 8);
        }
#pragma unroll
        for (int t = 0; t < 4; t++) {    // B: 256 rows = 2048 chunks
            const int p = t * 512 + tid;
            const int r = p >> 3;
            const int c = (p & 7) ^ (r & 7);
            async16(X + (size_t)(mb + r) * K + k0 + c * 8,
                    Bb + (t * 512 + wv * 64) * 8);
        }
    };

    stage(0, 0);                         // prologue: step 0 -> buf 0
    for (int s = 0; s < NSTEP; s++) {
        const int set = s & 1;
        __syncthreads();                 // buf[set] staging drained; fence
        if (s + 1 < NSTEP) stage(set ^ 1, (s + 1) * 64);

        const bf16_t* Ab = lds[set];
        const bf16_t* Bb = lds[set] + AELEM;

        bf16x8 a0[3][2], a1[3][2], b0[2][2], b1[2][2];

        // ---- phase 1: Q(0,0) -- load a0 (i=0..2), b0 (j=0..1) ----
#pragma unroll
        for (int i = 0; i < 3; i++) {
            const int r = wm * 96 + i * 16 + l15;
            a0[i][0] = *reinterpret_cast<const bf16x8*>(
                Ab + r * 64 + ((qd ^ (r & 7)) * 8));
            a0[i][1] = *reinterpret_cast<const bf16x8*>(
                Ab + r * 64 + (((4 + qd) ^ (r & 7)) * 8));
        }
#pragma unroll
        for (int j = 0; j < 2; j++) {
            const int r = wn * 64 + j * 16 + l15;
            b0[j][0] = *reinterpret_cast<const bf16x8*>(
                Bb + r * 64 + ((qd ^ (r & 7)) * 8));
            b0[j][1] = *reinterpret_cast<const bf16x8*>(
                Bb + r * 64 + (((4 + qd) ^ (r & 7)) * 8));
        }
        __builtin_amdgcn_s_setprio(1);
#pragma unroll
        for (int i = 0; i < 3; i++)
#pragma unroll
            for (int j = 0; j < 2; j++) {
                acc[i][j] = MFMA16(a0[i][0], b0[j][0], acc[i][j]);
                acc[i][j] = MFMA16(a0[i][1], b0[j][1], acc[i][j]);
            }
        __builtin_amdgcn_s_setprio(0);
        pbar();

        // ---- phase 2: Q(1,0) -- load a1 (i=3..5), reuse b0 ----
#pragma unroll
        for (int i = 0; i < 3; i++) {
            const int r = wm * 96 + (i + 3) * 16 + l15;
            a1[i][0] = *reinterpret_cast<const bf16x8*>(
                Ab + r * 64 + ((qd ^ (r & 7)) * 8));
            a1[i][1] = *reinterpret_cast<const bf16x8*>(
                Ab + r * 64 + (((4 + qd) ^ (r & 7)) * 8));
        }
        __builtin_amdgcn_s_setprio(1);
#pragma unroll
        for (int i = 0; i < 3; i++)
#pragma unroll
            for (int j = 0; j < 2; j++) {
                acc[i + 3][j] = MFMA16(a1[i][0], b0[j][0], acc[i + 3][j]);
                acc[i + 3][j] = MFMA16(a1[i][1], b0[j][1], acc[i + 3][j]);
            }
        __builtin_amdgcn_s_setprio(0);
        pbar();

        // ---- phase 3: Q(1,1) -- load b1 (j=2..3), reuse a1 ----
#pragma unroll
        for (int j = 0; j < 2; j++) {
            const int r = wn * 64 + (j + 2) * 16 + l15;
            b1[j][0] = *reinterpret_cast<const bf16x8*>(
                Bb + r * 64 + ((qd ^ (r & 7)) * 8));
            b1[j][1] = *reinterpret_cast<const bf16x8*>(
                Bb + r * 64 + (((4 + qd) ^ (r & 7)) * 8));
        }
        __builtin_amdgcn_s_setprio(1);
#pragma unroll
        for (int i = 0; i < 3; i++)
#pragma unroll
            for (int j = 0; j < 2; j++) {
                acc[i + 3][j + 2] = MFMA16(a1[i][0], b1[j][0], acc[i + 3][j + 2]);
                acc[i + 3][j + 2] = MFMA16(a1[i][1], b1[j][1], acc[i + 3][j + 2]);
            }
        __builtin_amdgcn_s_setprio(0);
        pbar();

        // ---- phase 4: Q(0,1) -- reuse a0, b1 (no reads) ----
        __builtin_amdgcn_s_setprio(1);
#pragma unroll
        for (int i = 0; i < 3; i++)
#pragma unroll
            for (int j = 0; j < 2; j++) {
                acc[i][j + 2] = MFMA16(a0[i][0], b1[j][0], acc[i][j + 2]);
                acc[i][j + 2] = MFMA16(a0[i][1], b1[j][1], acc[i][j + 2]);
            }
        __builtin_amdgcn_s_setprio(0);
    }

    // ---- epilogue: bias + per-i scale; V third transposed into vT ----
#pragma unroll
    for (int i = 0; i < 6; i++) {
        const int f0i = fb + wm * 96 + i * 16;       // 16-aligned group base
        const int f0  = f0i + qd * 4;
        const float scale = (f0i < 1024) ? 0.125f * LOG2E : 1.0f;
        const bool vblk = (f0i >= 2048);
        float bs[4];
#pragma unroll
        for (int r = 0; r < 4; r++) bs[r] = bias[f0 + r];
#pragma unroll
        for (int j = 0; j < 4; j++) {
            const int m = mb + wn * 64 + j * 16 + l15;
            if (vblk) {
                const int sIdx = m >> 1;          // B = 2 row interleave
                const int b2   = (m & 1) << 4;    // b*16
#pragma unroll
                for (int r = 0; r < 4; r++) {
                    const int fv = f0 + r - 2048;
                    vtp[(size_t)((b2 + (fv >> 6)) * 64 + (fv & 63)) * 2048 + sIdx] =
                        (bf16_t)(acc[i][j][r] + bs[r]);
                }
            } else {
                bf16x4 o;
#pragma unroll
                for (int r = 0; r < 4; r++)
                    o[r] = (bf16_t)((acc[i][j][r] + bs[r]) * scale);
                *reinterpret_cast<bf16x4*>(qkv + (size_t)m * 3072 + f0) = o;
            }
        }
    }
}

// ---------------------------------------------------------------------------
// Output projection GEMM -- 64(f) x 256(m) tile, BK=64, 8 waves, 2-sub-phase
// schedule, 256 blocks = 1/CU (R10: ~neutral vs 2-phase; kept).
// ---------------------------------------------------------------------------
__global__ __launch_bounds__(512, 2) void gemm_out(
    const bf16_t* __restrict__ W, const bf16_t* __restrict__ X,
    const float* __restrict__ bias, float* __restrict__ out)
{
    constexpr int K = 1024;
    constexpr int NSTEP = K / 64;        // 16
    constexpr int AELEM = 64 * 64;       // 8 KB
    constexpr int BELEM = 256 * 64;      // 32 KB

    __shared__ bf16_t lds[2][AELEM + BELEM];   // 80 KB total

    const int tid  = threadIdx.x;        // 0..511
    const int lane = tid & 63;
    const int wv   = tid >> 6;           // 0..7
    const int wm   = wv >> 2;            // f-half (32 rows each)
    const int wn   = wv & 3;             // m-quarter (64 rows each)
    const int l15  = lane & 15;
    const int qd   = lane >> 4;

    const int id = blockIdx.x;           // 0..255
    const int x8 = id & 7, k = id >> 3;  // k 0..31
    const int mb = ((k & 1) * 8 + x8) * 256;
    const int fb = (k >> 1) * 64;

    f32x4 acc[2][4] = {};                // [i: f frag 0..1][j: m frag 0..3]

    auto stage = [&](int set, int k0) {
        bf16_t* Ab = lds[set];
        bf16_t* Bb = lds[set] + AELEM;
        {                                // A: 64 rows = 512 chunks (1/thread)
            const int p = tid;
            const int r = p >> 3;
            const int c = (p & 7) ^ (r & 7);
            async16(W + (size_t)(fb + r) * K + k0 + c * 8,
                    Ab + (wv * 64) * 8);
        }
#pragma unroll
        for (int t = 0; t < 4; t++) {    // B: 256 rows = 2048 chunks
            const int p = t * 512 + tid;
            const int r = p >> 3;
            const int c = (p & 7) ^ (r & 7);
            async16(X + (size_t)(mb + r) * K + k0 + c * 8,
                    Bb + (t * 512 + wv * 64) * 8);
        }
    };

    stage(0, 0);
    for (int s = 0; s < NSTEP; s++) {
        const int set = s & 1;
        __syncthreads();                 // buf[set] staging drained; fence
        if (s + 1 < NSTEP) stage(set ^ 1, (s + 1) * 64);

        const bf16_t* Ab = lds[set];
        const bf16_t* Bb = lds[set] + AELEM;

        bf16x8 a[2][2], b0[2][2], b1[2][2];

        // ---- sub-phase 1: all a + b-half 0 (j=0..1) ----
#pragma unroll
        for (int i = 0; i < 2; i++) {
            const int r = wm * 32 + i * 16 + l15;
            a[i][0] = *reinterpret_cast<const bf16x8*>(
                Ab + r * 64 + ((qd ^ (r & 7)) * 8));
            a[i][1] = *reinterpret_cast<const bf16x8*>(
                Ab + r * 64 + (((4 + qd) ^ (r & 7)) * 8));
        }
#pragma unroll
        for (int j = 0; j < 2; j++) {
            const int r = wn * 64 + j * 16 + l15;
            b0[j][0] = *reinterpret_cast<const bf16x8*>(
                Bb + r * 64 + ((qd ^ (r & 7)) * 8));
            b0[j][1] = *reinterpret_cast<const bf16x8*>(
                Bb + r * 64 + (((4 + qd) ^ (r & 7)) * 8));
        }
        __builtin_amdgcn_s_setprio(1);
#pragma unroll
        for (int i = 0; i < 2; i++)
#pragma unroll
            for (int j = 0; j < 2; j++) {
                acc[i][j] = MFMA16(a[i][0], b0[j][0], acc[i][j]);
                acc[i][j] = MFMA16(a[i][1], b0[j][1], acc[i][j]);
            }
        __builtin_amdgcn_s_setprio(0);
        pbar();

        // ---- sub-phase 2: b-half 1 (j=2..3), reuse a ----
#pragma unroll
        for (int j = 0; j < 2; j++) {
            const int r = wn * 64 + (j + 2) * 16 + l15;
            b1[j][0] = *reinterpret_cast<const bf16x8*>(
                Bb + r * 64 + ((qd ^ (r & 7)) * 8));
            b1[j][1] = *reinterpret_cast<const bf16x8*>(
                Bb + r * 64 + (((4 + qd) ^ (r & 7)) * 8));
        }
        __builtin_amdgcn_s_setprio(1);
#pragma unroll
        for (int i = 0; i < 2; i++)
#pragma unroll
            for (int j = 0; j < 2; j++) {
                acc[i][j + 2] = MFMA16(a[i][0], b1[j][0], acc[i][j + 2]);
                acc[i][j + 2] = MFMA16(a[i][1], b1[j][1], acc[i][j + 2]);
            }
        __builtin_amdgcn_s_setprio(0);
    }

    // ---- epilogue: bias, f32 stores ----
#pragma unroll
    for (int i = 0; i < 2; i++) {
        const int f0 = fb + wm * 32 + i * 16 + qd * 4;
        float bs[4];
#pragma unroll
        for (int r = 0; r < 4; r++) bs[r] = bias[f0 + r];
#pragma unroll
        for (int j = 0; j < 4; j++) {
            const int m = mb + wn * 64 + j * 16 + l15;
            float4 o;
            o.x = acc[i][j][0] + bs[0];
            o.y = acc[i][j][1] + bs[1];
            o.z = acc[i][j][2] + bs[2];
            o.w = acc[i][j][3] + bs[3];
            *reinterpret_cast<float4*>(out + (size_t)m * 1024 + f0) = o;
        }
    }
}

// ---------------------------------------------------------------------------
// Flash attention with IN-BLOCK KV-split x2 (exact R2 kernel, verified
// 54-55 us across R2/R6/R7/R8/R10 -- the committed local optimum. Ledger of
// failed perturbations: R1 more waves (spill), R3 smaller q-blocks (reg-tile
// loss), R4/R9 register P-lag (spill / VGPR cap), R5/R11 V-direct-from-
// global (vmcnt in-order retirement serializes the K prefetch)).
// Block = 4 waves / 128 q. Grid 32 bh x 16 = 512 blocks, 2/CU.
// ---------------------------------------------------------------------------
__global__ __launch_bounds__(256, 2) void flash_attn(
    const bf16_t* __restrict__ qkv, const bf16_t* __restrict__ vT,
    bf16_t* __restrict__ attn, int S, int B)
{
    const int E3 = 3072, E = 1024;
    const int bh = blockIdx.x, b = bh >> 4, h = bh & 15;
    const int tid = threadIdx.x, lane = tid & 63, wv = tid >> 6;  // 0..3
    const int qw = wv & 1;               // q sub-block (64 q each)
    const int pr = wv >> 1;              // KV half
    const int l31 = lane & 31, half = lane >> 5;

    __shared__ bf16_t Kt[2][2][64 * 64];  // [pair][set]; chunk c at c^(r&7)
    __shared__ bf16_t Vt[2][2][64 * 64];  // [pair][set]; row d, chunk c at c^(d&7)
    __shared__ float  lsh[2][64];

    const int q0 = blockIdx.y * 128 + qw * 64;

    bf16x8 qf[2][4];                     // Q[q][k = ks*16 + half*8 + j]
#pragma unroll
    for (int qt = 0; qt < 2; qt++) {
        const bf16_t* qp = qkv + (size_t)((q0 + qt * 32 + l31) * B + b) * E3 + h * 64;
#pragma unroll
        for (int ks = 0; ks < 4; ks++)
            qf[qt][ks] = *reinterpret_cast<const bf16x8*>(qp + ks * 16 + half * 8);
    }

    f32x16 oacc[2][2] = {};              // [qt][d-tile]; row=d col=q
    float lrun[2] = {0.0f, 0.0f};

    auto stage = [&](int set, int kv) {
#pragma unroll
        for (int t = 0; t < 4; t++) {
            const int p = (qw * 4 + t) * 64 + lane;     // phys chunk 0..511
            const int r = p >> 3, cl = (p & 7) ^ (r & 7);
            async16(qkv + (size_t)((kv + r) * B + b) * E3 + E + h * 64 + cl * 8,
                    &Kt[pr][set][(qw * 4 + t) * 512]);
            async16(vT + (size_t)(bh * 64 + r) * 2048 + kv + cl * 8,
                    &Vt[pr][set][(qw * 4 + t) * 512]);
        }
    };

    const int kvbase = pr * (S / 2);
    const int NIT = S / 128;             // 16 iters of 64 per pair

    stage(0, kvbase);
    int set = 0;
    for (int it = 0; it < NIT; it++) {
        __syncthreads();                 // buf[set] ready; buf[set^1] free
        if (it + 1 < NIT) stage(set ^ 1, kvbase + (it + 1) * 64);

        const bf16_t* K_ = Kt[pr][set];
        const bf16_t* V_ = Vt[pr][set];

        union PF { unsigned u[4]; bf16x8 v; };
        PF pf[2][4];
#pragma unroll
        for (int nt = 0; nt < 2; nt++) {
            const int r = nt * 32 + l31;
            const int r7 = r & 7;
            bf16x8 kf[4];
#pragma unroll
            for (int ks = 0; ks < 4; ks++)
                kf[ks] = *reinterpret_cast<const bf16x8*>(
                    K_ + r * 64 + (((ks * 2 + half) ^ r7) * 8));
#pragma unroll
            for (int qt = 0; qt < 2; qt++) {
                f32x16 st = {};
                __builtin_amdgcn_s_setprio(1);
#pragma unroll
                for (int ks = 0; ks < 4; ks++)
                    st = MFMA32(kf[ks], qf[qt][ks], st);
                __builtin_amdgcn_s_setprio(0);
                float ls = 0.0f;
                unsigned q8[8];
#pragma unroll
                for (int g = 0; g < 4; g++) {
                    const float p0 = __builtin_amdgcn_exp2f(st[4 * g]);
                    const float p1 = __builtin_amdgcn_exp2f(st[4 * g + 1]);
                    const float p2 = __builtin_amdgcn_exp2f(st[4 * g + 2]);
                    const float p3 = __builtin_amdgcn_exp2f(st[4 * g + 3]);
                    ls += (p0 + p1) + (p2 + p3);
                    q8[2 * g]     = pack2(p0, p1);
                    q8[2 * g + 1] = pack2(p2, p3);
                }
                lrun[qt] += ls;
                pl32swap(q8[0], q8[2]); pl32swap(q8[1], q8[3]);
                pl32swap(q8[4], q8[6]); pl32swap(q8[5], q8[7]);
                pf[qt][nt * 2 + 0].u[0] = q8[0]; pf[qt][nt * 2 + 0].u[1] = q8[1];
                pf[qt][nt * 2 + 0].u[2] = q8[2]; pf[qt][nt * 2 + 0].u[3] = q8[3];
                pf[qt][nt * 2 + 1].u[0] = q8[4]; pf[qt][nt * 2 + 1].u[1] = q8[5];
                pf[qt][nt * 2 + 1].u[2] = q8[6]; pf[qt][nt * 2 + 1].u[3] = q8[7];
            }
        }
        __builtin_amdgcn_s_setprio(1);
#pragma unroll
        for (int kn = 0; kn < 4; kn++)
#pragma unroll
            for (int dt = 0; dt < 2; dt++) {
                const int d = dt * 32 + l31;
                bf16x8 vf = *reinterpret_cast<const bf16x8*>(
                    V_ + d * 64 + (((kn * 2 + half) ^ (d & 7)) * 8));
                oacc[0][dt] = MFMA32(vf, pf[0][kn].v, oacc[0][dt]);
                oacc[1][dt] = MFMA32(vf, pf[1][kn].v, oacc[1][dt]);
            }
        __builtin_amdgcn_s_setprio(0);
        set ^= 1;
    }

    // --- Epilogue: merge the two KV halves through LDS, normalize, store ---
    __syncthreads();                     // all K/V reads done; LDS reusable
    float lr[2];
#pragma unroll
    for (int qt = 0; qt < 2; qt++) lr[qt] = lrun[qt] + __shfl_xor(lrun[qt], 32);

    // fp32 scratch overlays Kt (32 KB = 2 regions x 64q x 64d), d-major
    float* fo = reinterpret_cast<float*>(&Kt[0][0][0]) + qw * 4096;

    if (pr == 1) {
#pragma unroll
        for (int qt = 0; qt < 2; qt++) {
            const int ql = qt * 32 + l31;
            lsh[qw][ql] = lr[qt];        // both halves write same value
#pragma unroll
            for (int dt = 0; dt < 2; dt++)
#pragma unroll
                for (int g = 0; g < 4; g++)
#pragma unroll
                    for (int r = 0; r < 4; r++) {
                        const int d = dt * 32 + g * 8 + half * 4 + r;
                        fo[d * 64 + ql] = oacc[qt][dt][4 * g + r];
                    }
        }
    }
    __syncthreads();
    if (pr == 0) {
#pragma unroll
        for (int qt = 0; qt < 2; qt++) {
            const int ql = qt * 32 + l31;
            const float inv = 1.0f / (lr[qt] + lsh[qw][ql]);
            const int qrow = q0 + qt * 32 + l31;
#pragma unroll
            for (int dt = 0; dt < 2; dt++)
#pragma unroll
                for (int g = 0; g < 4; g++) {
                    bf16x4 o;
#pragma unroll
                    for (int r = 0; r < 4; r++) {
                        const int d = dt * 32 + g * 8 + half * 4 + r;
                        o[r] = (bf16_t)((oacc[qt][dt][4 * g + r] + fo[d * 64 + ql]) * inv);
                    }
                    *reinterpret_cast<bf16x4*>(attn + (size_t)(qrow * B + b) * E +
                                               h * 64 + dt * 32 + g * 8 + half * 4) = o;
                }
        }
    }
}

extern "C" void kernel_launch(void* const* d_in, const int* in_sizes, int n_in,
                              void* d_out, int out_size, void* d_ws, size_t ws_size,
                              hipStream_t stream) {
    const float* x  = (const float*)d_in[0];
    const float* wi = (const float*)d_in[1];
    const float* bi = (const float*)d_in[2];
    const float* wo = (const float*)d_in[3];
    const float* bo = (const float*)d_in[4];
    float* out = (float*)d_out;

    const int S = 2048, B = 2, E = 1024;
    const int M = S * B;

    // Workspace layout:
    //   xb [M,1024] bf16  -- X in bf16; dead after QKV GEMM
    //   wib[3072,1024]    -- W_in bf16
    //   wob[1024,1024]    -- W_out bf16
    //   qkv[M,3072]       -- Q,K written by GEMM; V third left unwritten
    //   vT [32][64][2048] -- V transposed, written by the GEMM epilogue
    //   attn = xb overlay -- flash output (xb dead by then)
    bf16_t* xb   = (bf16_t*)d_ws;
    bf16_t* wib  = xb  + (size_t)M * E;
    bf16_t* wob  = wib + (size_t)3 * E * E;
    bf16_t* qkv  = wob + (size_t)E * E;
    bf16_t* vT   = qkv + (size_t)M * 3 * E;
    bf16_t* attn = xb;

    // 0) fused fp32 -> bf16
    const int n0 = M * E, n1 = 3 * E * E, n2 = E * E;
    conv3<<<(n0 + n1 + n2) / 8 / 256, 256, 0, stream>>>(x, wi, wo, xb, n0, n1);

    // 1) QKV projection: 192x256 4-phase template, 256 blocks = 1/CU;
    //    V third transposed into vT; qscale folded into q.
    gemm_qkv<<<256, 512, 0, stream>>>(wib, xb, bi, qkv, vT);

    // 2) Flash attention (exact R2 kernel; attn overlays dead xb)
    flash_attn<<<dim3(B * 16, S / 128), 256, 0, stream>>>(qkv, vT, attn, S, B);

    // 3) Output projection: 64x256 phased template, 256 blocks = 1/CU
    gemm_out<<<256, 512, 0, stream>>>(wob, attn, bo, out);
}